// Round 4
// baseline (170.182 us; speedup 1.0000x reference)
//
#include <hip/hip_runtime.h>
#include <hip/hip_bf16.h>

#define S_LEN  2048
#define HDIM   1024
#define NHEADS 16
#define HEADD  64
#define BATCH  2
#define MTOT   (BATCH * S_LEN)          // 4096
#define K2EXP  0.04508422f              // log2(e)/32 (folded into Wq/bq)

typedef __attribute__((ext_vector_type(8)))  __bf16 bf16x8;
typedef __attribute__((ext_vector_type(4)))  __bf16 bf16x4;
typedef __attribute__((ext_vector_type(4)))  float  f32x4;
typedef __attribute__((ext_vector_type(16))) float  f32x16;

__device__ __forceinline__ void gload16(const void* g, void* l) {
  __builtin_amdgcn_global_load_lds(
      (const __attribute__((address_space(1))) void*)g,
      (__attribute__((address_space(3))) void*)l, 16, 0, 0);
}
// swizzled LDS read: rows are 64 bf16 = 128B = 8 slots of 16B; slot ^= (row&7)
__device__ __forceinline__ bf16x8 lds_rd(const __bf16* base, int row, int bcol) {
  const char* p = (const char*)base + row * 128 + (bcol ^ ((row & 7) << 4));
  return *(const bf16x8*)p;
}
__device__ __forceinline__ unsigned cvtpk_bf16(float lo, float hi) {
  unsigned r;
  asm("v_cvt_pk_bf16_f32 %0, %1, %2" : "=v"(r) : "v"(lo), "v"(hi));
  return r;
}
__device__ __forceinline__ void plswap(unsigned& a, unsigned& b) {
  asm volatile("v_permlane32_swap_b32 %0, %1" : "+v"(a), "+v"(b));
}

// ========================================================== f32 -> bf16 ===
__global__ __launch_bounds__(256)
void cvt_kernel(const float* __restrict__ q, const float* __restrict__ k,
                const float* __restrict__ v, __bf16* __restrict__ Qc,
                __bf16* __restrict__ Kc, __bf16* __restrict__ Vc)
{
  const int z = blockIdx.z;
  const float* src = (z == 0) ? q : (z == 1) ? k : v;
  __bf16* dst = (z == 0) ? Qc : (z == 1) ? Kc : Vc;
  const size_t i = ((size_t)blockIdx.x * 256 + threadIdx.x) * 8;
  const float4 a = *(const float4*)&src[i];
  const float4 c = *(const float4*)&src[i + 4];
  bf16x8 o;
  o[0] = (__bf16)a.x; o[1] = (__bf16)a.y; o[2] = (__bf16)a.z; o[3] = (__bf16)a.w;
  o[4] = (__bf16)c.x; o[5] = (__bf16)c.y; o[6] = (__bf16)c.z; o[7] = (__bf16)c.w;
  *(bf16x8*)&dst[i] = o;
}

// ============================================== mask -> transposed bits ===
__global__ __launch_bounds__(256)
void maskpack_kernel(const int* __restrict__ mask, unsigned* __restrict__ mbT)
{
  const size_t idx = (size_t)blockIdx.x * 256 + threadIdx.x;
  const int m = mask[idx];
  const unsigned long long bal = __ballot(m != 0);
  if ((threadIdx.x & 63) == 0) {
    const int b   = (int)(idx >> 22);
    const int qq  = (int)(idx >> 11) & 2047;
    const int kvw = ((int)idx & 2047) >> 5;
    mbT[((size_t)b * 64 + kvw) * S_LEN + qq]       = (unsigned)bal;
    mbT[((size_t)b * 64 + kvw + 1) * S_LEN + qq]   = (unsigned)(bal >> 32);
  }
}

// ===================================================== weight transpose ===
// W[k][n] f32 -> Wt[n][k] bf16; z==0 (Wq) additionally scaled by K2EXP.
__global__ __launch_bounds__(256)
void transw_kernel(const float* __restrict__ Wq, const float* __restrict__ Wk,
                   const float* __restrict__ Wv, const float* __restrict__ Wfc,
                   __bf16* __restrict__ Wt)
{
  __shared__ float T[64][65];
  const int z = blockIdx.z;
  const float* W = (z == 0) ? Wq : (z == 1) ? Wk : (z == 2) ? Wv : Wfc;
  const float sc = (z == 0) ? K2EXP : 1.0f;
  __bf16* O = Wt + (size_t)z * HDIM * HDIM;
  const int k0 = blockIdx.x * 64, n0 = blockIdx.y * 64;
  const int tid = threadIdx.x;
  const int r  = tid >> 4;
  const int c4 = (tid & 15) * 4;
  #pragma unroll
  for (int p = 0; p < 4; ++p) {
    const int row = r + p * 16;
    const float4 vv = *(const float4*)&W[(size_t)(k0 + row) * HDIM + n0 + c4];
    T[row][c4 + 0] = vv.x; T[row][c4 + 1] = vv.y;
    T[row][c4 + 2] = vv.z; T[row][c4 + 3] = vv.w;
  }
  __syncthreads();
  #pragma unroll
  for (int p = 0; p < 4; ++p) {
    const int n = r + p * 16;
    bf16x4 o;
    #pragma unroll
    for (int i = 0; i < 4; ++i) o[i] = (__bf16)(T[c4 + i][n] * sc);
    *(bf16x4*)&O[(size_t)(n0 + n) * HDIM + k0 + c4] = o;
  }
}

// ================================================================== GEMM ===
// 128x128 tile, BK=64, dbuf, global_load_lds, XCD-swizzled block mapping.
// MODE 0: out bf16 (+bias*bscale). MODE 1: out f32 (+bias+resid).
// MODE 2: out = V^T per head (bf16) for attention.
template<int MODE>
__device__ __forceinline__ void gemm_body(
    const __bf16* __restrict__ A, const __bf16* __restrict__ Wt,
    const float* __restrict__ bias, float bscale,
    const float* __restrict__ resid,
    __bf16* __restrict__ Ob, float* __restrict__ Of, __bf16* __restrict__ Vtg)
{
  __shared__ __bf16 As[2][128][64];
  __shared__ __bf16 Bs[2][128][64];
  const int tid = threadIdx.x, lane = tid & 63, w = tid >> 6;
  const int fr = lane & 15, k8 = (lane >> 4) * 8;
  const int wr = w >> 1, wc = w & 1;
  // XCD-aware swizzle (nwg per z = 256, %8==0 -> bijective)
  const int f   = blockIdx.x + gridDim.x * blockIdx.y;
  const int cpx = (gridDim.x * gridDim.y) >> 3;
  const int fs  = (f & 7) * cpx + (f >> 3);
  const int m0 = (fs / gridDim.x) * 128, n0 = (fs % gridDim.x) * 128;
  const int srow8 = lane >> 3, slot = lane & 7;

  f32x4 acc[4][4] = {};

  #define G_STAGE(kt, bf)                                                    \
    {                                                                        \
      _Pragma("unroll")                                                      \
      for (int c = 0; c < 4; ++c) {                                          \
        const int ra = w * 32 + c * 8 + srow8;                               \
        gload16(&A[(size_t)(m0 + ra) * HDIM + (kt) * 64 + ((slot ^ (ra & 7)) * 8)], \
                (void*)&As[bf][w * 32 + c * 8][0]);                          \
      }                                                                      \
      _Pragma("unroll")                                                      \
      for (int c = 0; c < 4; ++c) {                                          \
        const int rb = w * 32 + c * 8 + srow8;                               \
        gload16(&Wt[(size_t)(n0 + rb) * HDIM + (kt) * 64 + ((slot ^ (rb & 7)) * 8)], \
                (void*)&Bs[bf][w * 32 + c * 8][0]);                          \
      }                                                                      \
    }

  #define G_COMPUTE(bf)                                                      \
    {                                                                        \
      _Pragma("unroll")                                                      \
      for (int kk = 0; kk < 64; kk += 32) {                                  \
        bf16x8 a[4], b[4];                                                   \
        _Pragma("unroll")                                                    \
        for (int i = 0; i < 4; ++i)                                          \
          a[i] = lds_rd(&As[bf][0][0], wr * 64 + i * 16 + fr, (kk + k8) * 2);\
        _Pragma("unroll")                                                    \
        for (int j = 0; j < 4; ++j)                                          \
          b[j] = lds_rd(&Bs[bf][0][0], wc * 64 + j * 16 + fr, (kk + k8) * 2);\
        _Pragma("unroll")                                                    \
        for (int i = 0; i < 4; ++i)                                          \
          _Pragma("unroll")                                                  \
          for (int j = 0; j < 4; ++j)                                        \
            acc[i][j] = __builtin_amdgcn_mfma_f32_16x16x32_bf16(a[i], b[j], acc[i][j], 0, 0, 0); \
      }                                                                      \
    }

  G_STAGE(0, 0)
  for (int kt = 0; kt < 15; ++kt) {
    G_STAGE(kt + 1, (kt + 1) & 1)
    asm volatile("s_waitcnt vmcnt(8)" ::: "memory");
    __builtin_amdgcn_s_barrier();
    __builtin_amdgcn_sched_barrier(0);
    __builtin_amdgcn_s_setprio(1);
    G_COMPUTE(kt & 1)
    __builtin_amdgcn_s_setprio(0);
    __builtin_amdgcn_sched_barrier(0);
    __builtin_amdgcn_s_barrier();
  }
  asm volatile("s_waitcnt vmcnt(0)" ::: "memory");
  __builtin_amdgcn_s_barrier();
  G_COMPUTE(1)

  const int rg = (lane >> 4) * 4;
  #pragma unroll
  for (int i = 0; i < 4; ++i) {
    #pragma unroll
    for (int j = 0; j < 4; ++j) {
      const int col = n0 + wc * 64 + j * 16 + fr;
      if constexpr (MODE == 2) {
        const int h = col >> 6, hd = col & 63;
        const int row = m0 + wr * 64 + i * 16 + rg;
        const int bq = row >> 11, qq = row & 2047;
        bf16x4 o;
        #pragma unroll
        for (int r = 0; r < 4; ++r) o[r] = (__bf16)(acc[i][j][r] + bias[col]);
        *(bf16x4*)&Vtg[(((size_t)bq * NHEADS + h) * HEADD + hd) * S_LEN + qq] = o;
      } else {
        #pragma unroll
        for (int r = 0; r < 4; ++r) {
          const int row = m0 + wr * 64 + i * 16 + rg + r;
          if constexpr (MODE == 0) {
            Ob[(size_t)row * HDIM + col] = (__bf16)(acc[i][j][r] + bias[col] * bscale);
          } else {
            Of[(size_t)row * HDIM + col] =
                acc[i][j][r] + bias[col] + resid[(size_t)row * HDIM + col];
          }
        }
      }
    }
  }
  #undef G_STAGE
  #undef G_COMPUTE
}

__global__ __launch_bounds__(256)
void qk_kernel(const __bf16* __restrict__ Qc, const __bf16* __restrict__ Kc,
               const __bf16* __restrict__ Wt,
               const float* __restrict__ bq, const float* __restrict__ bk,
               __bf16* __restrict__ Qb, __bf16* __restrict__ Kb)
{
  const int z = blockIdx.z;
  gemm_body<0>(z ? Kc : Qc, Wt + (size_t)z * HDIM * HDIM, z ? bk : bq,
               z ? 1.0f : K2EXP, nullptr, z ? Kb : Qb, nullptr, nullptr);
}

__global__ __launch_bounds__(256)
void vproj_kernel(const __bf16* __restrict__ Vc, const __bf16* __restrict__ Wt,
                  const float* __restrict__ bv, __bf16* __restrict__ Vtg)
{
  gemm_body<2>(Vc, Wt + (size_t)2 * HDIM * HDIM, bv, 1.0f, nullptr,
               nullptr, nullptr, Vtg);
}

__global__ __launch_bounds__(256)
void fc_kernel(const __bf16* __restrict__ A, const __bf16* __restrict__ Wt,
               const float* __restrict__ bias, const float* __restrict__ resid,
               float* __restrict__ Of)
{
  gemm_body<1>(A, Wt + (size_t)3 * HDIM * HDIM, bias, 1.0f, resid,
               nullptr, Of, nullptr);
}

// ============================================================= attention ===
// 4 waves x 32 q = 128 q/block; grid 32 bh x 16 -> 512 blocks = 2/CU so two
// independent schedules overlap MFMA and softmax phases. Swapped QK^T:
// lane owns q = lane&31; kv in regs: kv = (reg&3)+8*(reg>>2)+4*(lane>>5).
// Q pre-scaled by log2(e)/32 -> exp2 direct. setprio around MFMA clusters.
__global__ __launch_bounds__(256)
void attn_kernel(const __bf16* __restrict__ Qb, const __bf16* __restrict__ Kb,
                 const __bf16* __restrict__ Vtg, const unsigned* __restrict__ mbT,
                 __bf16* __restrict__ AO)
{
  __shared__ __bf16 Ks[2][64][64];
  __shared__ __bf16 Vt[2][64][64];
  __shared__ __align__(16) float Lsm[4][32];

  const int bh = blockIdx.x, b = bh >> 4, h = bh & 15;
  const int tid = threadIdx.x, lane = tid & 63, w = tid >> 6;
  const int fr = lane & 31, hi = lane >> 5;
  const int qw = blockIdx.y * 128 + w * 32;
  const int q  = qw + fr;

  bf16x8 qf[4];
  #pragma unroll
  for (int st = 0; st < 4; ++st)
    qf[st] = *(const bf16x8*)&Qb[((size_t)b * S_LEN + q) * HDIM + h * HEADD + st * 16 + hi * 8];

  // staging: wave w covers rows [w*16, w*16+16), two 8-row chunks per matrix
  const int srow = w * 16 + (lane >> 3), slot = lane & 7;
  const __bf16* ksrc = Kb  + ((size_t)b * S_LEN + srow) * HDIM + h * HEADD + (slot ^ (srow & 7)) * 8;
  const __bf16* vsrc = Vtg + ((size_t)bh * HEADD + srow) * S_LEN + (slot ^ (srow & 7)) * 8;
  const unsigned* mrow = mbT + (size_t)b * 64 * S_LEN + q;

  f32x16 o0 = {}, o1 = {};
  float lsum = 0.f;
  unsigned mv0, mv1, nv0 = 0, nv1 = 0;

  mv0 = mrow[0];
  mv1 = mrow[S_LEN];
  gload16(ksrc,            (void*)&Ks[0][w * 16][0]);
  gload16(ksrc + 8 * HDIM, (void*)&Ks[0][w * 16 + 8][0]);
  gload16(vsrc,             (void*)&Vt[0][w * 16][0]);
  gload16(vsrc + 8 * S_LEN, (void*)&Vt[0][w * 16 + 8][0]);

  for (int t = 0; t < 32; ++t) {
    const int buf = t & 1;
    if (t < 31) {
      nv0 = mrow[(size_t)(2 * t + 2) * S_LEN];
      nv1 = mrow[(size_t)(2 * t + 3) * S_LEN];
      const __bf16* kp = ksrc + (size_t)(t + 1) * 64 * HDIM;
      const __bf16* vp = vsrc + (t + 1) * 64;
      gload16(kp,            (void*)&Ks[buf ^ 1][w * 16][0]);
      gload16(kp + 8 * HDIM, (void*)&Ks[buf ^ 1][w * 16 + 8][0]);
      gload16(vp,             (void*)&Vt[buf ^ 1][w * 16][0]);
      gload16(vp + 8 * S_LEN, (void*)&Vt[buf ^ 1][w * 16 + 8][0]);
      asm volatile("s_waitcnt vmcnt(6)" ::: "memory");
    } else {
      asm volatile("s_waitcnt vmcnt(0)" ::: "memory");
    }
    __builtin_amdgcn_s_barrier();
    __builtin_amdgcn_sched_barrier(0);

    // ---- S^T = K Q^T
    f32x16 s0 = {}, s1 = {};
    __builtin_amdgcn_s_setprio(1);
    #pragma unroll
    for (int st = 0; st < 4; ++st) {
      const bf16x8 ka0 = lds_rd(&Ks[buf][0][0], fr,      st * 32 + hi * 16);
      const bf16x8 ka1 = lds_rd(&Ks[buf][0][0], 32 + fr, st * 32 + hi * 16);
      s0 = __builtin_amdgcn_mfma_f32_32x32x16_bf16(ka0, qf[st], s0, 0, 0, 0);
      s1 = __builtin_amdgcn_mfma_f32_32x32x16_bf16(ka1, qf[st], s1, 0, 0, 0);
    }
    __builtin_amdgcn_s_setprio(0);

    // ---- p = exp2(s) (scale pre-folded), masked -> 0
    float pp[32];
    const int kb = 4 * hi;
    #pragma unroll
    for (int j = 0; j < 16; ++j) {
      const int kvl = (j & 3) + 8 * (j >> 2) + kb;
      const float e0 = __builtin_amdgcn_exp2f(s0[j]);
      const float e1 = __builtin_amdgcn_exp2f(s1[j]);
      pp[j]      = ((mv0 >> kvl) & 1u) ? e0 : 0.f;
      pp[16 + j] = ((mv1 >> kvl) & 1u) ? e1 : 0.f;
      lsum += pp[j] + pp[16 + j];
    }

    // ---- P -> PV A-frags (cvt_pk + permlane32_swap)
    bf16x8 pa[4];
    #pragma unroll
    for (int g = 0; g < 4; ++g) {
      const int o = (g >> 1) * 16 + (g & 1) * 8;
      unsigned x  = cvtpk_bf16(pp[o + 0], pp[o + 1]);
      unsigned x2 = cvtpk_bf16(pp[o + 2], pp[o + 3]);
      unsigned y  = cvtpk_bf16(pp[o + 4], pp[o + 5]);
      unsigned y2 = cvtpk_bf16(pp[o + 6], pp[o + 7]);
      plswap(x, y);
      plswap(x2, y2);
      union { unsigned u[4]; bf16x8 v; } uu;
      uu.u[0] = x; uu.u[1] = x2; uu.u[2] = y; uu.u[3] = y2;
      pa[g] = uu.v;
    }

    // ---- O += P V
    __builtin_amdgcn_s_setprio(1);
    #pragma unroll
    for (int g = 0; g < 4; ++g) {
      const bf16x8 vb0 = lds_rd(&Vt[buf][0][0], fr,      g * 32 + hi * 16);
      const bf16x8 vb1 = lds_rd(&Vt[buf][0][0], 32 + fr, g * 32 + hi * 16);
      o0 = __builtin_amdgcn_mfma_f32_32x32x16_bf16(pa[g], vb0, o0, 0, 0, 0);
      o1 = __builtin_amdgcn_mfma_f32_32x32x16_bf16(pa[g], vb1, o1, 0, 0, 0);
    }
    __builtin_amdgcn_s_setprio(0);

    mv0 = nv0; mv1 = nv1;
    __builtin_amdgcn_sched_barrier(0);
    __builtin_amdgcn_s_barrier();
  }

  const float lt = lsum + __shfl_xor(lsum, 32);
  if (hi == 0) Lsm[w][fr] = lt;
  #pragma unroll
  for (int g = 0; g < 4; ++g) {
    const f32x4 L = *(const f32x4*)&Lsm[w][g * 8 + hi * 4];
    #pragma unroll
    for (int r = 0; r < 4; ++r) {
      const float inv = __builtin_amdgcn_rcpf(L[r]);
      const int j = g * 4 + r;
      const int qq = qw + g * 8 + hi * 4 + r;
      AO[((size_t)b * S_LEN + qq) * HDIM + h * HEADD + fr]      = (__bf16)(o0[j] * inv);
      AO[((size_t)b * S_LEN + qq) * HDIM + h * HEADD + 32 + fr] = (__bf16)(o1[j] * inv);
    }
  }
}

// ============================================================= layernorm ===
__global__ __launch_bounds__(256)
void ln_kernel(float* __restrict__ y, const float* __restrict__ gamma,
               const float* __restrict__ beta)
{
  __shared__ float red[8];
  const int tid = threadIdx.x;
  float* p = y + (size_t)blockIdx.x * HDIM;

  float4 vv = *(const float4*)&p[tid * 4];
  float s  = vv.x + vv.y + vv.z + vv.w;
  float ss = vv.x * vv.x + vv.y * vv.y + vv.z * vv.z + vv.w * vv.w;
  #pragma unroll
  for (int d = 1; d < 64; d <<= 1) {
    s  += __shfl_xor(s, d);
    ss += __shfl_xor(ss, d);
  }
  const int wid = tid >> 6;
  if ((tid & 63) == 0) { red[wid * 2] = s; red[wid * 2 + 1] = ss; }
  __syncthreads();
  s  = red[0] + red[2] + red[4] + red[6];
  ss = red[1] + red[3] + red[5] + red[7];
  const float mean = s * (1.0f / HDIM);
  const float var  = ss * (1.0f / HDIM) - mean * mean;
  const float inv  = rsqrtf(var + 1e-5f);

  const float4 g  = *(const float4*)&gamma[tid * 4];
  const float4 bt = *(const float4*)&beta[tid * 4];
  vv.x = (vv.x - mean) * inv * g.x + bt.x;
  vv.y = (vv.y - mean) * inv * g.y + bt.y;
  vv.z = (vv.z - mean) * inv * g.z + bt.z;
  vv.w = (vv.w - mean) * inv * g.w + bt.w;
  *(float4*)&p[tid * 4] = vv;
}

// ================================================================ launch ===
extern "C" void kernel_launch(void* const* d_in, const int* in_sizes, int n_in,
                              void* d_out, int out_size, void* d_ws, size_t ws_size,
                              hipStream_t stream) {
  const float* q     = (const float*)d_in[0];
  const float* k     = (const float*)d_in[1];
  const float* v     = (const float*)d_in[2];
  const int*   mask  = (const int*)  d_in[3];
  const float* Wq    = (const float*)d_in[4];
  const float* bq    = (const float*)d_in[5];
  const float* Wk    = (const float*)d_in[6];
  const float* bk    = (const float*)d_in[7];
  const float* Wv    = (const float*)d_in[8];
  const float* bv    = (const float*)d_in[9];
  const float* Wfc   = (const float*)d_in[10];
  const float* bfc   = (const float*)d_in[11];
  const float* gamma = (const float*)d_in[12];
  const float* beta  = (const float*)d_in[13];
  float* out = (float*)d_out;

  char* ws = (char*)d_ws;
  const size_t MB16 = (size_t)MTOT * HDIM * 2;     // 8.39 MB per bf16 matrix
  unsigned* mbT = (unsigned*)ws;                   // 1 MB
  __bf16* Wt  = (__bf16*)(ws + (1u << 20));        // 8 MB
  __bf16* Qc  = (__bf16*)(ws + (1u << 20) + 4 * (size_t)HDIM * HDIM * 2);
  __bf16* Kc  = (__bf16*)((char*)Qc + MB16);
  __bf16* Vc  = (__bf16*)((char*)Kc + MB16);
  __bf16* Qb  = (__bf16*)((char*)Vc + MB16);
  __bf16* Kb  = (__bf16*)((char*)Qb + MB16);
  __bf16* Vtg = (__bf16*)((char*)Kb + MB16);       // V^T written by vproj
  __bf16* AO  = Kc;   // alias: Kc dead after qk_kernel

  const dim3 blk(256);

  cvt_kernel<<<dim3(MTOT * HDIM / 8 / 256, 1, 3), blk, 0, stream>>>(q, k, v, Qc, Kc, Vc);
  maskpack_kernel<<<dim3((size_t)BATCH * S_LEN * S_LEN / 256), blk, 0, stream>>>(mask, mbT);
  transw_kernel<<<dim3(16, 16, 4), blk, 0, stream>>>(Wq, Wk, Wv, Wfc, Wt);

  qk_kernel<<<dim3(HDIM / 128, MTOT / 128, 2), blk, 0, stream>>>(
      Qc, Kc, Wt, bq, bk, Qb, Kb);
  vproj_kernel<<<dim3(HDIM / 128, MTOT / 128), blk, 0, stream>>>(
      Vc, Wt, bv, Vtg);

  attn_kernel<<<dim3(BATCH * NHEADS, S_LEN / 128), blk, 0, stream>>>(
      Qb, Kb, Vtg, mbT, AO);

  fc_kernel<<<dim3(HDIM / 128, MTOT / 128), blk, 0, stream>>>(
      AO, Wt, bfc, q, out);

  ln_kernel<<<dim3(MTOT), blk, 0, stream>>>(out, gamma, beta);
}